// Round 6
// baseline (358.601 us; speedup 1.0000x reference)
//
#include <hip/hip_runtime.h>

using u16 = unsigned short;
using s16x8 = __attribute__((ext_vector_type(8))) short;   // 8 bf16 (4 VGPRs)
using f32x4 = __attribute__((ext_vector_type(4))) float;

#define DEVI __device__ __forceinline__

constexpr int AN = 9, NB = 10, NN = 4096, DORI = 2048, DAPP = 512, NCLS = 21, QCOLS = 160;

// output offsets (f32 elements) in return order
constexpr size_t O0 = 0;                 // output            (4096,4)
constexpr size_t O1 = 16384;             // output_beta       (4096,4)
constexpr size_t O2 = 32768;             // alpha_softmax     (9,4096,4)
constexpr size_t O3 = 180224;            // beta_softmax      (9,4096,4)
constexpr size_t O4 = 327680;            // delta_pred_offset (9,4096,4)
constexpr size_t O5 = 475136;            // delta_pred_offset (9,4096,4)
constexpr size_t O6 = 622592;            // alpha             (9,4096,4)
constexpr size_t O7 = 770048;            // beta_out          (9,4096,4)
constexpr size_t O8 = 917504;            // cls_score         (9,4096,21)
constexpr size_t O9 = 1691648;           // alpha_softmax_cls (9,4096,1)
constexpr size_t O10 = 1728512;          // beta_softmax_cls
constexpr size_t O11 = 1765376;          // alpha_cls
constexpr size_t O12 = 1802240;          // beta_out_cls

DEVI u16 f2b(float f) {                   // f32 -> bf16 RNE (internal use only)
  unsigned u = __float_as_uint(f);
  unsigned r = (u + 0x7fffu + ((u >> 16) & 1u)) >> 16;
  return (u16)r;
}

DEVI uint4 pack8(float4 u, float4 v) {    // 8 f32 -> 8 bf16 packed
  uint4 r;
  r.x = (unsigned)f2b(u.x) | ((unsigned)f2b(u.y) << 16);
  r.y = (unsigned)f2b(u.z) | ((unsigned)f2b(u.w) << 16);
  r.z = (unsigned)f2b(v.x) | ((unsigned)f2b(v.y) << 16);
  r.w = (unsigned)f2b(v.z) | ((unsigned)f2b(v.w) << 16);
  return r;
}

DEVI void gload_lds16(const u16* g, u16* l) {   // 16B global -> LDS direct
  __builtin_amdgcn_global_load_lds(
      (const __attribute__((address_space(1))) void*)g,
      (__attribute__((address_space(3))) void*)l, 16, 0, 0);
}

// ================= fused prep: transpose_att | pack_q | pack_small =================
// block ranges: [0,4096) att, [4096,7296) pack_q, [7296,7368) pack_small
__global__ __launch_bounds__(256) void prep(const float* __restrict__ att,
                                            const float* __restrict__ wq,
                                            const float* __restrict__ wqc,
                                            const float* __restrict__ wk,
                                            const float* __restrict__ wkc,
                                            const float* __restrict__ aw,
                                            const float* __restrict__ bb,
                                            const float* __restrict__ awc,
                                            const float* __restrict__ cw,
                                            u16* __restrict__ attB,
                                            u16* __restrict__ Wq,
                                            u16* __restrict__ Wsm) {
  const int b = blockIdx.x, tid = threadIdx.x;
  if (b < 4096) {                                   // attB[c][d] = att[d][c]
    int t = b * 256 + tid;
    int c = t / DORI, d = t % DORI;
    attB[t] = f2b(att[(size_t)d * DAPP + c]);
  } else if (b < 7296) {                            // Wq[b][160][512]
    int t = (b - 4096) * 256 + tid;
    int bq = t / (QCOLS * DAPP);
    int r = t % (QCOLS * DAPP);
    int col = r / DAPP, d = r % DAPP;
    float v;
    if (bq < 9) {
      if (col < 128) v = wq[(size_t)bq * DAPP * 128 + (size_t)d * 128 + col];
      else           v = wqc[(size_t)bq * DAPP * 32 + (size_t)d * 32 + (col - 128)];
    } else {
      if (col < 128) v = wk[(size_t)d * 128 + col];
      else           v = wkc[(size_t)d * 32 + (col - 128)];
    }
    Wq[t] = f2b(v);
  } else {                                          // Wsmall[a][32][2048]
    int t = (b - 7296) * 256 + tid;
    if (t >= AN * DORI) return;
    int a = t / DORI, f = t % DORI;
    u16* Wa = Wsm + (size_t)a * 32 * DORI;
    for (int c = 0; c < 4; ++c)  Wa[c * DORI + f]       = f2b(aw[((size_t)a * DORI + f) * 4 + c]);
    for (int c = 0; c < 4; ++c)  Wa[(4 + c) * DORI + f] = f2b(bb[((size_t)a * DORI + f) * 4 + c]);
    for (int c = 0; c < 21; ++c) Wa[(8 + c) * DORI + f] = f2b(cw[((size_t)a * DORI + f) * 21 + c]);
    Wa[29 * DORI + f] = f2b(awc[(size_t)a * DORI + f]);
    Wa[30 * DORI + f] = 0;
    Wa[31 * DORI + f] = 0;
  }
}

// ================= mega: one feature pass ==========================================
// Per 64-row tile and batch z (0-8 features, 9 = gt):
//   off[z]   = relu(A @ attB^T)   (512 cols, all 8 waves, 64x64 wave tiles)
//   smallf   = A @ Wsmall[z]^T    (32 cols, extra fragment on waves 0,1; z<9 only)
// A staged f32->bf16 in-register (2-deep prefetch); B via global_load_lds from L2.
__global__ __launch_bounds__(512) void mega(const float* __restrict__ feat,
                                            const float* __restrict__ gt,
                                            const u16* __restrict__ attB,
                                            const u16* __restrict__ Wsm,
                                            u16* __restrict__ offb,
                                            float* __restrict__ smallf,
                                            float* __restrict__ cls_out) {
  __shared__ __align__(16) u16 As[64 * 32];
  __shared__ __align__(16) u16 Bs[544 * 32];
  const int tid = threadIdx.x, lane = tid & 63, w = tid >> 6;
  const int tileM = blockIdx.y * 64, z = blockIdx.z;
  const float* Ab = ((z < 9) ? feat + (size_t)z * NN * DORI : gt) + (size_t)tileM * DORI;
  const u16* Wb = Wsm + (size_t)((z < 9) ? z : 0) * 32 * DORI;

  f32x4 acc[4][4], accS[4];
#pragma unroll
  for (int i = 0; i < 4; ++i) {
#pragma unroll
    for (int j = 0; j < 4; ++j) acc[i][j] = (f32x4){0.f, 0.f, 0.f, 0.f};
    accS[i] = (f32x4){0.f, 0.f, 0.f, 0.f};
  }

  const int arow = tid >> 2, acol = (tid & 3) * 8;   // tid<256 stages A
  const bool aact = tid < 256;
  uint4 raA, raB;
  auto loadA = [&](int k0, uint4& r) {
    const float* s = Ab + (size_t)arow * DORI + k0 + acol;
    r = pack8(*(const float4*)s, *(const float4*)(s + 4));
  };
  if (aact) { loadA(0, raA); loadA(32, raB); }

  auto stageB = [&](int k0) {
#pragma unroll
    for (int i = 0; i < 4; ++i) {                    // rows 0-511: attB
      int c = tid + i * 512;
      gload_lds16(attB + (size_t)(c >> 2) * DORI + k0 + (c & 3) * 8, Bs + c * 8);
    }
    if (tid < 128) {                                 // rows 512-543: Wsmall
      int c = 2048 + tid;
      gload_lds16(Wb + (size_t)((c >> 2) - 512) * DORI + k0 + (c & 3) * 8, Bs + c * 8);
    }
  };

  const u16* Arow = As + (lane & 15) * 32 + (lane >> 4) * 8;
  const u16* Brow = Bs + (w * 64 + (lane & 15)) * 32 + (lane >> 4) * 8;
  const u16* BrowS = Bs + (512 + w * 16 + (lane & 15)) * 32 + (lane >> 4) * 8;

  auto step = [&](int k0, uint4 ra) {
    if (aact) *(uint4*)(As + (size_t)tid * 8) = ra;
    stageB(k0);
    __syncthreads();
    s16x8 af[4], bfr[4];
#pragma unroll
    for (int i = 0; i < 4; ++i) af[i] = *(const s16x8*)(Arow + i * 16 * 32);
#pragma unroll
    for (int j = 0; j < 4; ++j) bfr[j] = *(const s16x8*)(Brow + j * 16 * 32);
#pragma unroll
    for (int i = 0; i < 4; ++i)
#pragma unroll
      for (int j = 0; j < 4; ++j)
        acc[i][j] = __builtin_amdgcn_mfma_f32_16x16x32_bf16(af[i], bfr[j], acc[i][j], 0, 0, 0);
    if (w < 2) {
      s16x8 bs = *(const s16x8*)BrowS;
#pragma unroll
      for (int i = 0; i < 4; ++i)
        accS[i] = __builtin_amdgcn_mfma_f32_16x16x32_bf16(af[i], bs, accS[i], 0, 0, 0);
    }
    __syncthreads();
  };

  for (int k0 = 0; k0 < DORI; k0 += 64) {
    uint4 curA = raA, curB = raB;
    if (aact && k0 + 64 < DORI) loadA(k0 + 64, raA);
    step(k0, curA);
    if (aact && k0 + 96 < DORI) loadA(k0 + 96, raB);
    step(k0 + 32, curB);
  }

  // epilogue: off (all waves)
#pragma unroll
  for (int i = 0; i < 4; ++i) {
    const int row = tileM + i * 16 + (lane >> 4) * 4;
    const int col = w * 64 + (lane & 15);
#pragma unroll
    for (int j = 0; j < 4; ++j)
#pragma unroll
      for (int q = 0; q < 4; ++q)
        offb[((size_t)z * NN + row + q) * DAPP + col + j * 16] =
            f2b(fmaxf(acc[i][j][q], 0.f));
  }
  // epilogue: smallf + cls (waves 0,1; z<9)
  if (w < 2 && z < 9) {
    const int cs = w * 16 + (lane & 15);
#pragma unroll
    for (int i = 0; i < 4; ++i) {
      const int row = tileM + i * 16 + (lane >> 4) * 4;
#pragma unroll
      for (int q = 0; q < 4; ++q) {
        const size_t an = (size_t)z * NN + row + q;
        smallf[an * 32 + cs] = accS[i][q];
        if (cs >= 8 && cs <= 28) cls_out[an * 21 + (cs - 8)] = accS[i][q];
      }
    }
  }
}

// ================= bf16 GEMM with global_load_lds staging (key path) ===============
template<int BM, int BN, int WM, int WN, bool RELU, bool OUTBF, bool SWZ>
__global__ __launch_bounds__(WM * WN * 64)
void gemm_glds(const u16* __restrict__ A, long sA, const u16* __restrict__ B, long sB,
               void* __restrict__ Cv, long sC, int N, int K) {
  constexpr int THREADS = WM * WN * 64;
  constexpr int WTM = BM / WM, WTN = BN / WN;
  constexpr int FM = WTM / 16, FN = WTN / 16;
  constexpr int ACHN = BM * 4, BCHN = BN * 4;
  constexpr int ACH = (ACHN + THREADS - 1) / THREADS;
  constexpr int BCH = (BCHN + THREADS - 1) / THREADS;
  constexpr bool AFULL = (ACHN % THREADS) == 0, BFULL = (BCHN % THREADS) == 0;

  __shared__ __align__(16) u16 As[BM * 32];
  __shared__ __align__(16) u16 Bs[BN * 32];

  int bx = blockIdx.x, by = blockIdx.y, bz = blockIdx.z;
  if constexpr (SWZ) {
    int gx = gridDim.x, gy = gridDim.y;
    int h = bx + gx * (by + gy * bz);
    int nwg = gx * gy * (int)gridDim.z;
    int cpx = nwg >> 3;
    int l = (h & 7) * cpx + (h >> 3);
    bx = l % gx; l /= gx; by = l % gy; bz = l / gy;
  }

  const int tid = threadIdx.x, lane = tid & 63, wave = tid >> 6;
  const int wm = wave % WM, wn = wave / WM;
  const int tileN = bx * BN, tileM = by * BM;
  const u16* Ab = A + (size_t)bz * sA + (size_t)tileM * K;
  const u16* Bb = B + (size_t)bz * sB + (size_t)tileN * K;

  f32x4 acc[FM][FN];
#pragma unroll
  for (int i = 0; i < FM; ++i)
#pragma unroll
    for (int j = 0; j < FN; ++j) acc[i][j] = (f32x4){0.f, 0.f, 0.f, 0.f};

  const u16* Arow = As + (wm * WTM + (lane & 15)) * 32 + (lane >> 4) * 8;
  const u16* Brow = Bs + (wn * WTN + (lane & 15)) * 32 + (lane >> 4) * 8;

  for (int k0 = 0; k0 < K; k0 += 32) {
#pragma unroll
    for (int i = 0; i < ACH; ++i) {
      int c = tid + i * THREADS;
      if (AFULL || c < ACHN)
        gload_lds16(Ab + (size_t)(c >> 2) * K + k0 + (c & 3) * 8, As + c * 8);
    }
#pragma unroll
    for (int i = 0; i < BCH; ++i) {
      int c = tid + i * THREADS;
      if (BFULL || c < BCHN)
        gload_lds16(Bb + (size_t)(c >> 2) * K + k0 + (c & 3) * 8, Bs + c * 8);
    }
    __syncthreads();
    s16x8 af[FM], bfr[FN];
#pragma unroll
    for (int i = 0; i < FM; ++i) af[i] = *(const s16x8*)(Arow + i * 16 * 32);
#pragma unroll
    for (int j = 0; j < FN; ++j) bfr[j] = *(const s16x8*)(Brow + j * 16 * 32);
#pragma unroll
    for (int i = 0; i < FM; ++i)
#pragma unroll
      for (int j = 0; j < FN; ++j)
        acc[i][j] = __builtin_amdgcn_mfma_f32_16x16x32_bf16(af[i], bfr[j], acc[i][j], 0, 0, 0);
    __syncthreads();
  }

  const int r0 = tileM + wm * WTM + (lane >> 4) * 4;
  const int c0 = tileN + wn * WTN + (lane & 15);
#pragma unroll
  for (int i = 0; i < FM; ++i)
#pragma unroll
    for (int j = 0; j < FN; ++j)
#pragma unroll
      for (int q = 0; q < 4; ++q) {
        float v = acc[i][j][q];
        if (RELU) v = fmaxf(v, 0.f);
        size_t idx = (size_t)bz * sC + (size_t)(r0 + i * 16 + q) * N + (c0 + j * 16);
        if (OUTBF) ((u16*)Cv)[idx] = f2b(v);
        else       ((float*)Cv)[idx] = v;
      }
}

// ================= fused q-projection + beta epilogue ==============================
__global__ __launch_bounds__(256) void gemm2qb(const u16* __restrict__ offb,
                                               const u16* __restrict__ Wq,
                                               const float* __restrict__ keyf,
                                               const float* __restrict__ ious,
                                               float* __restrict__ betaf,
                                               float* __restrict__ betac) {
  constexpr int BM = 128, BN = 160;
  __shared__ __align__(16) u16 As[BM * 32];
  __shared__ __align__(16) u16 Bs[BN * 32];
  const int tid = threadIdx.x, lane = tid & 63, wave = tid >> 6;  // 4 waves on M
  const int tileM = blockIdx.x * BM;
  const int a = blockIdx.y;
  const u16* Ab = offb + ((size_t)a * NN + tileM) * DAPP;
  const u16* Bb = Wq + (size_t)a * QCOLS * DAPP;

  f32x4 acc[2][10];
#pragma unroll
  for (int i = 0; i < 2; ++i)
#pragma unroll
    for (int j = 0; j < 10; ++j) acc[i][j] = (f32x4){0.f, 0.f, 0.f, 0.f};

  const u16* Arow = As + (wave * 32 + (lane & 15)) * 32 + (lane >> 4) * 8;
  const u16* Brow = Bs + (lane & 15) * 32 + (lane >> 4) * 8;

  for (int k0 = 0; k0 < DAPP; k0 += 32) {
#pragma unroll
    for (int i = 0; i < 2; ++i) {          // ACHN = 512
      int c = tid + i * 256;
      gload_lds16(Ab + (size_t)(c >> 2) * DAPP + k0 + (c & 3) * 8, As + c * 8);
    }
#pragma unroll
    for (int i = 0; i < 3; ++i) {          // BCHN = 640
      int c = tid + i * 256;
      if (c < 640)
        gload_lds16(Bb + (size_t)(c >> 2) * DAPP + k0 + (c & 3) * 8, Bs + c * 8);
    }
    __syncthreads();
    s16x8 af[2], bfr[10];
#pragma unroll
    for (int i = 0; i < 2; ++i) af[i] = *(const s16x8*)(Arow + i * 16 * 32);
#pragma unroll
    for (int j = 0; j < 10; ++j) bfr[j] = *(const s16x8*)(Brow + j * 16 * 32);
#pragma unroll
    for (int i = 0; i < 2; ++i)
#pragma unroll
      for (int j = 0; j < 10; ++j)
        acc[i][j] = __builtin_amdgcn_mfma_f32_16x16x32_bf16(af[i], bfr[j], acc[i][j], 0, 0, 0);
    __syncthreads();
  }

  const float scale = 0.17677669529663687f;  // 1/sqrt(32)
  const int cg = lane & 15;
#pragma unroll
  for (int i = 0; i < 2; ++i)
#pragma unroll
    for (int q = 0; q < 4; ++q) {
      const int row = tileM + wave * 32 + i * 16 + (lane >> 4) * 4 + q;
      const float* kr = keyf + (size_t)row * QCOLS;
      float m = 0.f;
#pragma unroll
      for (int j = 0; j < 8; ++j) m += acc[i][j][q] * kr[cg + j * 16];
      float cl = acc[i][8][q] * kr[128 + cg] + acc[i][9][q] * kr[144 + cg];
      m += __shfl_xor(m, 4); m += __shfl_xor(m, 8);
      cl += __shfl_xor(cl, 1); cl += __shfl_xor(cl, 2);
      cl += __shfl_xor(cl, 4); cl += __shfl_xor(cl, 8);
      const float iou = ious[(size_t)a * NN + row];
      if (cg < 4)  betaf[((size_t)a * NN + row) * 4 + (lane & 3)] = m * scale - iou;
      if (cg == 0) betac[(size_t)a * NN + row] = cl * scale - iou;
    }
}

// ================= softmaxes + outputs (all f32), thread per n =====================
__global__ __launch_bounds__(256) void finalize(const float* __restrict__ smallf,
                                                const float* __restrict__ beta_ws,
                                                const float* __restrict__ betac_ws,
                                                const float* __restrict__ delta_rois,
                                                float* __restrict__ out) {
  int n = blockIdx.x * blockDim.x + threadIdx.x;
  if (n >= NN) return;

  for (int c = 0; c < 4; ++c) {
    float al[9], be[9], dp[9];
    float mA = -1e30f, mB = -1e30f;
    for (int a = 0; a < 9; ++a) {
      size_t an = (size_t)a * NN + n;
      al[a] = smallf[an * 32 + c];
      float off_ = smallf[an * 32 + 4 + c];
      dp[a] = delta_rois[an * 5 + 1 + c] + off_;
      be[a] = beta_ws[an * 4 + c];
      mA = fmaxf(mA, al[a]); mB = fmaxf(mB, be[a]);
    }
    float eA[9], eB[9], sA = 0.f, sB = 0.f;
    for (int a = 0; a < 9; ++a) {
      eA[a] = expf(al[a] - mA); sA += eA[a];
      eB[a] = expf(be[a] - mB); sB += eB[a];
    }
    float rA = 1.f / sA, rB = 1.f / sB;
    float ov = 0.f, obv = 0.f;
    for (int a = 0; a < 9; ++a) {
      size_t an = (size_t)a * NN + n;
      float as_ = eA[a] * rA, bs_ = eB[a] * rB;
      out[O2 + an * 4 + c] = as_;
      out[O3 + an * 4 + c] = bs_;
      out[O4 + an * 4 + c] = dp[a];
      out[O5 + an * 4 + c] = dp[a];
      out[O6 + an * 4 + c] = al[a];
      out[O7 + an * 4 + c] = be[a];
      ov += dp[a] * as_; obv += dp[a] * bs_;
    }
    out[O0 + (size_t)n * 4 + c] = ov;
    out[O1 + (size_t)n * 4 + c] = obv;
  }

  float ac[9], bc[9];
  float mA = -1e30f, mB = -1e30f;
  for (int a = 0; a < 9; ++a) {
    size_t an = (size_t)a * NN + n;
    ac[a] = smallf[an * 32 + 29];
    bc[a] = betac_ws[an];
    mA = fmaxf(mA, ac[a]); mB = fmaxf(mB, bc[a]);
  }
  float eA[9], eB[9], sA = 0.f, sB = 0.f;
  for (int a = 0; a < 9; ++a) {
    eA[a] = expf(ac[a] - mA); sA += eA[a];
    eB[a] = expf(bc[a] - mB); sB += eB[a];
  }
  float rA = 1.f / sA, rB = 1.f / sB;
  for (int a = 0; a < 9; ++a) {
    size_t an = (size_t)a * NN + n;
    out[O9 + an]  = eA[a] * rA;
    out[O10 + an] = eB[a] * rB;
    out[O11 + an] = ac[a];
    out[O12 + an] = bc[a];
  }
}

extern "C" void kernel_launch(void* const* d_in, const int* in_sizes, int n_in,
                              void* d_out, int out_size, void* d_ws, size_t ws_size,
                              hipStream_t stream) {
  const float* delta_rois = (const float*)d_in[1];
  const float* features   = (const float*)d_in[2];
  const float* gt_features= (const float*)d_in[3];
  const float* ious       = (const float*)d_in[4];
  const float* att        = (const float*)d_in[5];
  const float* w_k        = (const float*)d_in[6];
  const float* w_q        = (const float*)d_in[7];
  const float* alpha_w    = (const float*)d_in[8];
  const float* bbox       = (const float*)d_in[9];
  const float* w_k_cls    = (const float*)d_in[10];
  const float* w_q_cls    = (const float*)d_in[11];
  const float* alpha_w_cls= (const float*)d_in[12];
  const float* cls_w      = (const float*)d_in[13];
  float* out = (float*)d_out;

  char* ws = (char*)d_ws;
  u16* attB    = (u16*)ws;   ws += (size_t)DAPP * DORI * 2;       // 2.1 MB
  u16* Wq      = (u16*)ws;   ws += (size_t)NB * QCOLS * DAPP * 2; // 1.6 MB
  u16* Wsmall  = (u16*)ws;   ws += (size_t)AN * 32 * DORI * 2;    // 1.2 MB
  u16* offb    = (u16*)ws;   ws += (size_t)NB * NN * DAPP * 2;    // 42 MB (batch9 = gt_off)
  float* smallf= (float*)ws; ws += (size_t)AN * NN * 32 * 4;      // 4.7 MB
  float* keyf  = (float*)ws; ws += (size_t)NN * QCOLS * 4;        // 2.6 MB
  float* betaf = (float*)ws; ws += (size_t)AN * NN * 4 * 4;       // 2.4 MB
  float* betac = (float*)ws; ws += (size_t)AN * NN * 4;           // 0.15 MB
  // total ~57 MB

  // 1. fused prep (att transpose, Wq pack, Wsmall pack)
  prep<<<7368, 256, 0, stream>>>(att, w_q, w_q_cls, w_k, w_k_cls, alpha_w, bbox,
                                 alpha_w_cls, cls_w, attB, Wq, Wsmall);

  // 2. mega: off + smallf + cls in one feature pass
  dim3 gm(1, NN / 64, NB);
  mega<<<gm, 512, 0, stream>>>(features, gt_features, attB, Wsmall,
                               offb, smallf, out + O8);

  // 3. key = gt_off @ Wq[9]^T (batch 9) -> keyf f32
  dim3 gk(QCOLS / 32, NN / 128, 1);
  gemm_glds<128, 32, 4, 1, false, false, false><<<gk, 256, 0, stream>>>(
      offb + (size_t)9 * NN * DAPP, 0, Wq + (size_t)9 * QCOLS * DAPP, 0,
      keyf, 0, QCOLS, DAPP);

  // 4. fused q-projection + beta (batches 0-8)
  dim3 g2(NN / 128, AN, 1);
  gemm2qb<<<g2, 256, 0, stream>>>(offb, Wq, keyf, ious, betaf, betac);

  // 5. softmaxes + outputs
  finalize<<<NN / 256, 256, 0, stream>>>(smallf, betaf, betac, delta_rois, out);
}

// Round 7
// 348.123 us; speedup vs baseline: 1.0301x; 1.0301x over previous
//
#include <hip/hip_runtime.h>

using u16 = unsigned short;
using s16x8 = __attribute__((ext_vector_type(8))) short;   // 8 bf16 (4 VGPRs)
using f32x4 = __attribute__((ext_vector_type(4))) float;

#define DEVI __device__ __forceinline__

constexpr int AN = 9, NB = 10, NN = 4096, DORI = 2048, DAPP = 512, NCLS = 21, QCOLS = 160;

// output offsets (f32 elements) in return order
constexpr size_t O0 = 0;                 // output            (4096,4)
constexpr size_t O1 = 16384;             // output_beta       (4096,4)
constexpr size_t O2 = 32768;             // alpha_softmax     (9,4096,4)
constexpr size_t O3 = 180224;            // beta_softmax      (9,4096,4)
constexpr size_t O4 = 327680;            // delta_pred_offset (9,4096,4)
constexpr size_t O5 = 475136;            // delta_pred_offset (9,4096,4)
constexpr size_t O6 = 622592;            // alpha             (9,4096,4)
constexpr size_t O7 = 770048;            // beta_out          (9,4096,4)
constexpr size_t O8 = 917504;            // cls_score         (9,4096,21)
constexpr size_t O9 = 1691648;           // alpha_softmax_cls (9,4096,1)
constexpr size_t O10 = 1728512;          // beta_softmax_cls
constexpr size_t O11 = 1765376;          // alpha_cls
constexpr size_t O12 = 1802240;          // beta_out_cls

DEVI u16 f2b(float f) {                   // f32 -> bf16 RNE (internal use only)
  unsigned u = __float_as_uint(f);
  unsigned r = (u + 0x7fffu + ((u >> 16) & 1u)) >> 16;
  return (u16)r;
}

DEVI uint4 pack8(float4 u, float4 v) {    // 8 f32 -> 8 bf16 packed
  uint4 r;
  r.x = (unsigned)f2b(u.x) | ((unsigned)f2b(u.y) << 16);
  r.y = (unsigned)f2b(u.z) | ((unsigned)f2b(u.w) << 16);
  r.z = (unsigned)f2b(v.x) | ((unsigned)f2b(v.y) << 16);
  r.w = (unsigned)f2b(v.z) | ((unsigned)f2b(v.w) << 16);
  return r;
}

DEVI void gload_lds16(const u16* g, u16* l) {   // 16B global -> LDS direct
  __builtin_amdgcn_global_load_lds(
      (const __attribute__((address_space(1))) void*)g,
      (__attribute__((address_space(3))) void*)l, 16, 0, 0);
}

// ================= streaming f32 -> bf16 cast, 8 elems/thread ======================
__global__ __launch_bounds__(256) void cast_kernel(const float* __restrict__ src,
                                                   u16* __restrict__ dst, long n8) {
  long i = (long)blockIdx.x * blockDim.x + threadIdx.x;
  long stride = (long)gridDim.x * blockDim.x;
  for (; i < n8; i += stride) {
    float4 v0 = ((const float4*)src)[i * 2];
    float4 v1 = ((const float4*)src)[i * 2 + 1];
    ((uint4*)dst)[i] = pack8(v0, v1);
  }
}

// ================= fused prep: transpose_att | pack_q | pack_small | cast gt =======
// block ranges: [0,4096) att, [4096,7296) pack_q, [7296,7368) pack_small, [7368,11464) gt
__global__ __launch_bounds__(256) void prep(const float* __restrict__ att,
                                            const float* __restrict__ wq,
                                            const float* __restrict__ wqc,
                                            const float* __restrict__ wk,
                                            const float* __restrict__ wkc,
                                            const float* __restrict__ aw,
                                            const float* __restrict__ bb,
                                            const float* __restrict__ awc,
                                            const float* __restrict__ cw,
                                            const float* __restrict__ gt,
                                            u16* __restrict__ attB,
                                            u16* __restrict__ Wq,
                                            u16* __restrict__ Wsm,
                                            u16* __restrict__ featB9) {
  const int b = blockIdx.x, tid = threadIdx.x;
  if (b < 4096) {                                   // attB[c][d] = att[d][c]
    int t = b * 256 + tid;
    int c = t / DORI, d = t % DORI;
    attB[t] = f2b(att[(size_t)d * DAPP + c]);
  } else if (b < 7296) {                            // Wq[b][160][512]
    int t = (b - 4096) * 256 + tid;
    int bq = t / (QCOLS * DAPP);
    int r = t % (QCOLS * DAPP);
    int col = r / DAPP, d = r % DAPP;
    float v;
    if (bq < 9) {
      if (col < 128) v = wq[(size_t)bq * DAPP * 128 + (size_t)d * 128 + col];
      else           v = wqc[(size_t)bq * DAPP * 32 + (size_t)d * 32 + (col - 128)];
    } else {
      if (col < 128) v = wk[(size_t)d * 128 + col];
      else           v = wkc[(size_t)d * 32 + (col - 128)];
    }
    Wq[t] = f2b(v);
  } else if (b < 7368) {                            // Wsmall[a][32][2048]
    int t = (b - 7296) * 256 + tid;
    if (t >= AN * DORI) return;
    int a = t / DORI, f = t % DORI;
    u16* Wa = Wsm + (size_t)a * 32 * DORI;
    for (int c = 0; c < 4; ++c)  Wa[c * DORI + f]       = f2b(aw[((size_t)a * DORI + f) * 4 + c]);
    for (int c = 0; c < 4; ++c)  Wa[(4 + c) * DORI + f] = f2b(bb[((size_t)a * DORI + f) * 4 + c]);
    for (int c = 0; c < 21; ++c) Wa[(8 + c) * DORI + f] = f2b(cw[((size_t)a * DORI + f) * 21 + c]);
    Wa[29 * DORI + f] = f2b(awc[(size_t)a * DORI + f]);
    Wa[30 * DORI + f] = 0;
    Wa[31 * DORI + f] = 0;
  } else {                                          // gt_features f32 -> featB batch 9
    if (!featB9) return;
    long i = (long)(b - 7368) * 256 + tid;          // < NN*DORI/8 = 1048576
    float4 v0 = ((const float4*)gt)[i * 2];
    float4 v1 = ((const float4*)gt)[i * 2 + 1];
    ((uint4*)featB9)[i] = pack8(v0, v1);
  }
}

// ================= bf16 GEMM with global_load_lds staging ==========================
// C[M,N] = A[M,K] * Bt[N,K]^T ; all bf16 operands
template<int BM, int BN, int WM, int WN, bool RELU, bool OUTBF, bool SWZ>
__global__ __launch_bounds__(WM * WN * 64)
void gemm_glds(const u16* __restrict__ A, long sA, const u16* __restrict__ B, long sB,
               void* __restrict__ Cv, long sC, int N, int K) {
  constexpr int THREADS = WM * WN * 64;
  constexpr int WTM = BM / WM, WTN = BN / WN;
  constexpr int FM = WTM / 16, FN = WTN / 16;
  constexpr int ACHN = BM * 4, BCHN = BN * 4;
  constexpr int ACH = (ACHN + THREADS - 1) / THREADS;
  constexpr int BCH = (BCHN + THREADS - 1) / THREADS;
  constexpr bool AFULL = (ACHN % THREADS) == 0, BFULL = (BCHN % THREADS) == 0;

  __shared__ __align__(16) u16 As[BM * 32];
  __shared__ __align__(16) u16 Bs[BN * 32];

  int bx = blockIdx.x, by = blockIdx.y, bz = blockIdx.z;
  if constexpr (SWZ) {   // chunked XCD swizzle (nwg % 8 == 0 required)
    int gx = gridDim.x, gy = gridDim.y;
    int h = bx + gx * (by + gy * bz);
    int nwg = gx * gy * (int)gridDim.z;
    int cpx = nwg >> 3;
    int l = (h & 7) * cpx + (h >> 3);
    bx = l % gx; l /= gx; by = l % gy; bz = l / gy;
  }

  const int tid = threadIdx.x, lane = tid & 63, wave = tid >> 6;
  const int wm = wave % WM, wn = wave / WM;
  const int tileN = bx * BN, tileM = by * BM;
  const u16* Ab = A + (size_t)bz * sA + (size_t)tileM * K;
  const u16* Bb = B + (size_t)bz * sB + (size_t)tileN * K;

  f32x4 acc[FM][FN];
#pragma unroll
  for (int i = 0; i < FM; ++i)
#pragma unroll
    for (int j = 0; j < FN; ++j) acc[i][j] = (f32x4){0.f, 0.f, 0.f, 0.f};

  const u16* Arow = As + (wm * WTM + (lane & 15)) * 32 + (lane >> 4) * 8;
  const u16* Brow = Bs + (wn * WTN + (lane & 15)) * 32 + (lane >> 4) * 8;

  for (int k0 = 0; k0 < K; k0 += 32) {
#pragma unroll
    for (int i = 0; i < ACH; ++i) {
      int c = tid + i * THREADS;
      if (AFULL || c < ACHN)
        gload_lds16(Ab + (size_t)(c >> 2) * K + k0 + (c & 3) * 8, As + c * 8);
    }
#pragma unroll
    for (int i = 0; i < BCH; ++i) {
      int c = tid + i * THREADS;
      if (BFULL || c < BCHN)
        gload_lds16(Bb + (size_t)(c >> 2) * K + k0 + (c & 3) * 8, Bs + c * 8);
    }
    __syncthreads();
    s16x8 af[FM], bfr[FN];
#pragma unroll
    for (int i = 0; i < FM; ++i) af[i] = *(const s16x8*)(Arow + i * 16 * 32);
#pragma unroll
    for (int j = 0; j < FN; ++j) bfr[j] = *(const s16x8*)(Brow + j * 16 * 32);
#pragma unroll
    for (int i = 0; i < FM; ++i)
#pragma unroll
      for (int j = 0; j < FN; ++j)
        acc[i][j] = __builtin_amdgcn_mfma_f32_16x16x32_bf16(af[i], bfr[j], acc[i][j], 0, 0, 0);
    __syncthreads();
  }

  const int r0 = tileM + wm * WTM + (lane >> 4) * 4;
  const int c0 = tileN + wn * WTN + (lane & 15);
#pragma unroll
  for (int i = 0; i < FM; ++i)
#pragma unroll
    for (int j = 0; j < FN; ++j)
#pragma unroll
      for (int q = 0; q < 4; ++q) {
        float v = acc[i][j][q];
        if (RELU) v = fmaxf(v, 0.f);
        size_t idx = (size_t)bz * sC + (size_t)(r0 + i * 16 + q) * N + (c0 + j * 16);
        if (OUTBF) ((u16*)Cv)[idx] = f2b(v);
        else       ((float*)Cv)[idx] = v;
      }
}

// ================= gemm_small: smallf = featB @ Wsmall^T + fused cls out ===========
// fixed <BM=128, BN=32, WM=4, WN=1>, K=2048; batches 0-8
__global__ __launch_bounds__(256) void gemm_small(const u16* __restrict__ A,
                                                  const u16* __restrict__ Wsm,
                                                  float* __restrict__ smallf,
                                                  float* __restrict__ cls_out) {
  __shared__ __align__(16) u16 As[128 * 32];
  __shared__ __align__(16) u16 Bs[32 * 32];
  const int tid = threadIdx.x, lane = tid & 63, wave = tid >> 6;
  const int tileM = blockIdx.y * 128, bz = blockIdx.z;
  const u16* Ab = A + ((size_t)bz * NN + tileM) * DORI;
  const u16* Bb = Wsm + (size_t)bz * 32 * DORI;

  f32x4 acc[2][2];
#pragma unroll
  for (int i = 0; i < 2; ++i)
#pragma unroll
    for (int j = 0; j < 2; ++j) acc[i][j] = (f32x4){0.f, 0.f, 0.f, 0.f};

  const u16* Arow = As + (wave * 32 + (lane & 15)) * 32 + (lane >> 4) * 8;
  const u16* Brow = Bs + (lane & 15) * 32 + (lane >> 4) * 8;

  for (int k0 = 0; k0 < DORI; k0 += 32) {
#pragma unroll
    for (int i = 0; i < 2; ++i) {                   // ACHN = 512
      int c = tid + i * 256;
      gload_lds16(Ab + (size_t)(c >> 2) * DORI + k0 + (c & 3) * 8, As + c * 8);
    }
    if (tid < 128)                                  // BCHN = 128
      gload_lds16(Bb + (size_t)(tid >> 2) * DORI + k0 + (tid & 3) * 8, Bs + tid * 8);
    __syncthreads();
    s16x8 af[2], bfr[2];
#pragma unroll
    for (int i = 0; i < 2; ++i) af[i] = *(const s16x8*)(Arow + i * 16 * 32);
#pragma unroll
    for (int j = 0; j < 2; ++j) bfr[j] = *(const s16x8*)(Brow + j * 16 * 32);
#pragma unroll
    for (int i = 0; i < 2; ++i)
#pragma unroll
      for (int j = 0; j < 2; ++j)
        acc[i][j] = __builtin_amdgcn_mfma_f32_16x16x32_bf16(af[i], bfr[j], acc[i][j], 0, 0, 0);
    __syncthreads();
  }

#pragma unroll
  for (int i = 0; i < 2; ++i)
#pragma unroll
    for (int j = 0; j < 2; ++j)
#pragma unroll
      for (int q = 0; q < 4; ++q) {
        const int row = tileM + wave * 32 + i * 16 + (lane >> 4) * 4 + q;
        const int col = j * 16 + (lane & 15);
        const size_t an = (size_t)bz * NN + row;
        float v = acc[i][j][q];
        smallf[an * 32 + col] = v;
        if (col >= 8 && col <= 28) cls_out[an * 21 + (col - 8)] = v;
      }
}

// ================= fallback gemm1 (A = f32, reg-staged pack) =======================
template<int BM, int BN, int WM, int WN, bool RELU, bool OUTBF>
__global__ __launch_bounds__(WM * WN * 64)
void gemm_af32(const float* __restrict__ Av, const float* __restrict__ A2v, long sA,
               const u16* __restrict__ B, long sB,
               void* __restrict__ Cv, long sC, int N, int K) {
  constexpr int THREADS = WM * WN * 64;
  constexpr int WTM = BM / WM, WTN = BN / WN;
  constexpr int FM = WTM / 16, FN = WTN / 16;
  constexpr int ACH = (BM * 4) / THREADS;
  constexpr int BCHN = BN * 4;
  constexpr int BCH = (BCHN + THREADS - 1) / THREADS;
  constexpr bool BFULL = (BCHN % THREADS) == 0;

  __shared__ __align__(16) u16 As[BM * 32];
  __shared__ __align__(16) u16 Bs[BN * 32];

  const int tid = threadIdx.x, lane = tid & 63, wave = tid >> 6;
  const int wm = wave % WM, wn = wave / WM;
  const int tileN = blockIdx.x * BN, tileM = blockIdx.y * BM;
  const int batch = blockIdx.z;
  const float* base = (batch < 9) ? (Av + (size_t)batch * sA) : A2v;
  const float* Ab32 = base + (size_t)tileM * K;
  const u16* Bb = B + (size_t)batch * sB + (size_t)tileN * K;

  f32x4 acc[FM][FN];
#pragma unroll
  for (int i = 0; i < FM; ++i)
#pragma unroll
    for (int j = 0; j < FN; ++j) acc[i][j] = (f32x4){0.f, 0.f, 0.f, 0.f};

  uint4 ra[ACH], rb[BCH];
  auto load_t = [&](int k0) {
#pragma unroll
    for (int i = 0; i < ACH; ++i) {
      int c = tid + i * THREADS;
      const float* s = Ab32 + (size_t)(c >> 2) * K + k0 + (c & 3) * 8;
      ra[i] = pack8(*(const float4*)s, *(const float4*)(s + 4));
    }
#pragma unroll
    for (int i = 0; i < BCH; ++i) {
      int c = tid + i * THREADS;
      if (BFULL || c < BCHN)
        rb[i] = *(const uint4*)(Bb + (size_t)(c >> 2) * K + k0 + (c & 3) * 8);
    }
  };

  load_t(0);
  const u16* Arow = As + (wm * WTM + (lane & 15)) * 32 + (lane >> 4) * 8;
  const u16* Brow = Bs + (wn * WTN + (lane & 15)) * 32 + (lane >> 4) * 8;

  for (int k0 = 0; k0 < K; k0 += 32) {
    __syncthreads();
#pragma unroll
    for (int i = 0; i < ACH; ++i)
      *(uint4*)(As + (size_t)(tid + i * THREADS) * 8) = ra[i];
#pragma unroll
    for (int i = 0; i < BCH; ++i) {
      int c = tid + i * THREADS;
      if (BFULL || c < BCHN) *(uint4*)(Bs + (size_t)c * 8) = rb[i];
    }
    __syncthreads();
    if (k0 + 32 < K) load_t(k0 + 32);
    s16x8 af[FM], bfr[FN];
#pragma unroll
    for (int i = 0; i < FM; ++i) af[i] = *(const s16x8*)(Arow + i * 16 * 32);
#pragma unroll
    for (int j = 0; j < FN; ++j) bfr[j] = *(const s16x8*)(Brow + j * 16 * 32);
#pragma unroll
    for (int i = 0; i < FM; ++i)
#pragma unroll
      for (int j = 0; j < FN; ++j)
        acc[i][j] = __builtin_amdgcn_mfma_f32_16x16x32_bf16(af[i], bfr[j], acc[i][j], 0, 0, 0);
  }

  const int r0 = tileM + wm * WTM + (lane >> 4) * 4;
  const int c0 = tileN + wn * WTN + (lane & 15);
#pragma unroll
  for (int i = 0; i < FM; ++i)
#pragma unroll
    for (int j = 0; j < FN; ++j)
#pragma unroll
      for (int q = 0; q < 4; ++q) {
        float v = acc[i][j][q];
        if (RELU) v = fmaxf(v, 0.f);
        size_t idx = (size_t)batch * sC + (size_t)(r0 + i * 16 + q) * N + (c0 + j * 16);
        if (OUTBF) ((u16*)Cv)[idx] = f2b(v);
        else       ((float*)Cv)[idx] = v;
      }
}

// ================= cls copy (fallback path only) ===================================
__global__ __launch_bounds__(256) void cls_copy(const float* __restrict__ smallf,
                                                float* __restrict__ o) {
  int i = blockIdx.x * blockDim.x + threadIdx.x;
  if (i >= AN * NN * NCLS) return;
  int an = i / NCLS, c = i % NCLS;
  o[i] = smallf[(size_t)an * 32 + 8 + c];
}

// ================= fused q-projection + beta epilogue ==============================
__global__ __launch_bounds__(256) void gemm2qb(const u16* __restrict__ offb,
                                               const u16* __restrict__ Wq,
                                               const float* __restrict__ keyf,
                                               const float* __restrict__ ious,
                                               float* __restrict__ betaf,
                                               float* __restrict__ betac) {
  constexpr int BM = 128, BN = 160;
  __shared__ __align__(16) u16 As[BM * 32];
  __shared__ __align__(16) u16 Bs[BN * 32];
  const int tid = threadIdx.x, lane = tid & 63, wave = tid >> 6;  // 4 waves on M
  const int tileM = blockIdx.x * BM;
  const int a = blockIdx.y;
  const u16* Ab = offb + ((size_t)a * NN + tileM) * DAPP;
  const u16* Bb = Wq + (size_t)a * QCOLS * DAPP;

  f32x4 acc[2][10];
#pragma unroll
  for (int i = 0; i < 2; ++i)
#pragma unroll
    for (int j = 0; j < 10; ++j) acc[i][j] = (f32x4){0.f, 0.f, 0.f, 0.f};

  const u16* Arow = As + (wave * 32 + (lane & 15)) * 32 + (lane >> 4) * 8;
  const u16* Brow = Bs + (lane & 15) * 32 + (lane >> 4) * 8;

  for (int k0 = 0; k0 < DAPP; k0 += 32) {
#pragma unroll
    for (int i = 0; i < 2; ++i) {          // ACHN = 512
      int c = tid + i * 256;
      gload_lds16(Ab + (size_t)(c >> 2) * DAPP + k0 + (c & 3) * 8, As + c * 8);
    }
#pragma unroll
    for (int i = 0; i < 3; ++i) {          // BCHN = 640
      int c = tid + i * 256;
      if (c < 640)
        gload_lds16(Bb + (size_t)(c >> 2) * DAPP + k0 + (c & 3) * 8, Bs + c * 8);
    }
    __syncthreads();
    s16x8 af[2], bfr[10];
#pragma unroll
    for (int i = 0; i < 2; ++i) af[i] = *(const s16x8*)(Arow + i * 16 * 32);
#pragma unroll
    for (int j = 0; j < 10; ++j) bfr[j] = *(const s16x8*)(Brow + j * 16 * 32);
#pragma unroll
    for (int i = 0; i < 2; ++i)
#pragma unroll
      for (int j = 0; j < 10; ++j)
        acc[i][j] = __builtin_amdgcn_mfma_f32_16x16x32_bf16(af[i], bfr[j], acc[i][j], 0, 0, 0);
    __syncthreads();
  }

  const float scale = 0.17677669529663687f;  // 1/sqrt(32)
  const int cg = lane & 15;
#pragma unroll
  for (int i = 0; i < 2; ++i)
#pragma unroll
    for (int q = 0; q < 4; ++q) {
      const int row = tileM + wave * 32 + i * 16 + (lane >> 4) * 4 + q;
      const float* kr = keyf + (size_t)row * QCOLS;
      float m = 0.f;
#pragma unroll
      for (int j = 0; j < 8; ++j) m += acc[i][j][q] * kr[cg + j * 16];
      float cl = acc[i][8][q] * kr[128 + cg] + acc[i][9][q] * kr[144 + cg];
      m += __shfl_xor(m, 4); m += __shfl_xor(m, 8);
      cl += __shfl_xor(cl, 1); cl += __shfl_xor(cl, 2);
      cl += __shfl_xor(cl, 4); cl += __shfl_xor(cl, 8);
      const float iou = ious[(size_t)a * NN + row];
      if (cg < 4)  betaf[((size_t)a * NN + row) * 4 + (lane & 3)] = m * scale - iou;
      if (cg == 0) betac[(size_t)a * NN + row] = cl * scale - iou;
    }
}

// ================= softmaxes + outputs (all f32), thread per n =====================
__global__ __launch_bounds__(256) void finalize(const float* __restrict__ smallf,
                                                const float* __restrict__ beta_ws,
                                                const float* __restrict__ betac_ws,
                                                const float* __restrict__ delta_rois,
                                                float* __restrict__ out) {
  int n = blockIdx.x * blockDim.x + threadIdx.x;
  if (n >= NN) return;

  for (int c = 0; c < 4; ++c) {
    float al[9], be[9], dp[9];
    float mA = -1e30f, mB = -1e30f;
    for (int a = 0; a < 9; ++a) {
      size_t an = (size_t)a * NN + n;
      al[a] = smallf[an * 32 + c];
      float off_ = smallf[an * 32 + 4 + c];
      dp[a] = delta_rois[an * 5 + 1 + c] + off_;
      be[a] = beta_ws[an * 4 + c];
      mA = fmaxf(mA, al[a]); mB = fmaxf(mB, be[a]);
    }
    float eA[9], eB[9], sA = 0.f, sB = 0.f;
    for (int a = 0; a < 9; ++a) {
      eA[a] = expf(al[a] - mA); sA += eA[a];
      eB[a] = expf(be[a] - mB); sB += eB[a];
    }
    float rA = 1.f / sA, rB = 1.f / sB;
    float ov = 0.f, obv = 0.f;
    for (int a = 0; a < 9; ++a) {
      size_t an = (size_t)a * NN + n;
      float as_ = eA[a] * rA, bs_ = eB[a] * rB;
      out[O2 + an * 4 + c] = as_;
      out[O3 + an * 4 + c] = bs_;
      out[O4 + an * 4 + c] = dp[a];
      out[O5 + an * 4 + c] = dp[a];
      out[O6 + an * 4 + c] = al[a];
      out[O7 + an * 4 + c] = be[a];
      ov += dp[a] * as_; obv += dp[a] * bs_;
    }
    out[O0 + (size_t)n * 4 + c] = ov;
    out[O1 + (size_t)n * 4 + c] = obv;
  }

  float ac[9], bc[9];
  float mA = -1e30f, mB = -1e30f;
  for (int a = 0; a < 9; ++a) {
    size_t an = (size_t)a * NN + n;
    ac[a] = smallf[an * 32 + 29];
    bc[a] = betac_ws[an];
    mA = fmaxf(mA, ac[a]); mB = fmaxf(mB, bc[a]);
  }
  float eA[9], eB[9], sA = 0.f, sB = 0.f;
  for (int a = 0; a < 9; ++a) {
    eA[a] = expf(ac[a] - mA); sA += eA[a];
    eB[a] = expf(bc[a] - mB); sB += eB[a];
  }
  float rA = 1.f / sA, rB = 1.f / sB;
  for (int a = 0; a < 9; ++a) {
    size_t an = (size_t)a * NN + n;
    out[O9 + an]  = eA[a] * rA;
    out[O10 + an] = eB[a] * rB;
    out[O11 + an] = ac[a];
    out[O12 + an] = bc[a];
  }
}

extern "C" void kernel_launch(void* const* d_in, const int* in_sizes, int n_in,
                              void* d_out, int out_size, void* d_ws, size_t ws_size,
                              hipStream_t stream) {
  const float* delta_rois = (const float*)d_in[1];
  const float* features   = (const float*)d_in[2];
  const float* gt_features= (const float*)d_in[3];
  const float* ious       = (const float*)d_in[4];
  const float* att        = (const float*)d_in[5];
  const float* w_k        = (const float*)d_in[6];
  const float* w_q        = (const float*)d_in[7];
  const float* alpha_w    = (const float*)d_in[8];
  const float* bbox       = (const float*)d_in[9];
  const float* w_k_cls    = (const float*)d_in[10];
  const float* w_q_cls    = (const float*)d_in[11];
  const float* alpha_w_cls= (const float*)d_in[12];
  const float* cls_w      = (const float*)d_in[13];
  float* out = (float*)d_out;

  char* ws = (char*)d_ws;
  u16* attB    = (u16*)ws;   ws += (size_t)DAPP * DORI * 2;       // 2.1 MB
  u16* Wq      = (u16*)ws;   ws += (size_t)NB * QCOLS * DAPP * 2; // 1.6 MB
  u16* Wsmall  = (u16*)ws;   ws += (size_t)AN * 32 * DORI * 2;    // 1.2 MB
  u16* offb    = (u16*)ws;   ws += (size_t)NB * NN * DAPP * 2;    // 42 MB (batch9 = gt_off)
  float* smallf= (float*)ws; ws += (size_t)AN * NN * 32 * 4;      // 4.7 MB
  float* keyf  = (float*)ws; ws += (size_t)NN * QCOLS * 4;        // 2.6 MB
  float* betaf = (float*)ws; ws += (size_t)AN * NN * 4 * 4;       // 2.4 MB
  float* betac = (float*)ws; ws += (size_t)AN * NN * 4;           // 0.15 MB
  size_t base_bytes = (size_t)(ws - (char*)d_ws);
  size_t featB_bytes = (size_t)NB * NN * DORI * 2;                // 168 MB
  bool big = ws_size >= base_bytes + featB_bytes;
  u16* featB = big ? (u16*)ws : nullptr;

  // 1. fused prep (att transpose, Wq pack, Wsmall pack, gt cast -> featB[9])
  prep<<<11464, 256, 0, stream>>>(att, w_q, w_q_cls, w_k, w_k_cls, alpha_w, bbox,
                                  alpha_w_cls, cls_w, gt_features, attB, Wq, Wsmall,
                                  big ? featB + (size_t)AN * NN * DORI : nullptr);

  if (big) {
    // 2. streaming cast: features f32 -> featB[0..8] bf16 (full-BW)
    cast_kernel<<<2048, 256, 0, stream>>>(features, featB, (long)AN * NN * DORI / 8);

    // 3. smallf + cls from L3-warm featB (m97-structure, fused cls epilogue)
    dim3 gsm(1, NN / 128, AN);
    gemm_small<<<gsm, 256, 0, stream>>>(featB, Wsmall, smallf, out + O8);

    // 4. off = relu(featB @ attB^T) [10 batches, batch9 = gt]
    dim3 g1(DAPP / 128, NN / 128, NB);
    gemm_glds<128, 128, 2, 2, true, true, true><<<g1, 256, 0, stream>>>(
        featB, (long)NN * DORI, attB, 0, offb, (long)NN * DAPP, DAPP, DORI);
  } else {
    // fallback: reg-staged f32 GEMMs reading features directly
    dim3 g1(DAPP / 128, NN / 128, NB);
    gemm_af32<128, 128, 2, 2, true, true><<<g1, 256, 0, stream>>>(
        features, gt_features, (long)NN * DORI, attB, 0, offb, (long)NN * DAPP, DAPP, DORI);
    dim3 gsm(1, NN / 128, AN);
    gemm_af32<128, 32, 4, 1, false, false><<<gsm, 256, 0, stream>>>(
        features, nullptr, (long)NN * DORI, Wsmall, (long)32 * DORI,
        smallf, (long)NN * 32, 32, DORI);
    cls_copy<<<(AN * NN * NCLS + 255) / 256, 256, 0, stream>>>(smallf, out + O8);
  }

  // 5. key = gt_off @ Wq[9]^T (batch 9) -> keyf f32
  dim3 gk(QCOLS / 32, NN / 128, 1);
  gemm_glds<128, 32, 4, 1, false, false, false><<<gk, 256, 0, stream>>>(
      offb + (size_t)9 * NN * DAPP, 0, Wq + (size_t)9 * QCOLS * DAPP, 0,
      keyf, 0, QCOLS, DAPP);

  // 6. fused q-projection + beta (batches 0-8)
  dim3 g2(NN / 128, AN, 1);
  gemm2qb<<<g2, 256, 0, stream>>>(offb, Wq, keyf, ious, betaf, betac);

  // 7. softmaxes + outputs
  finalize<<<NN / 256, 256, 0, stream>>>(smallf, betaf, betac, delta_rois, out);
}

// Round 8
// 334.234 us; speedup vs baseline: 1.0729x; 1.0416x over previous
//
#include <hip/hip_runtime.h>

using u16 = unsigned short;
using s16x8 = __attribute__((ext_vector_type(8))) short;   // 8 bf16 (4 VGPRs)
using f32x4 = __attribute__((ext_vector_type(4))) float;

#define DEVI __device__ __forceinline__

constexpr int AN = 9, NB = 10, NN = 4096, DORI = 2048, DAPP = 512, NCLS = 21, QCOLS = 160;

// output offsets (f32 elements) in return order
constexpr size_t O0 = 0;                 // output            (4096,4)
constexpr size_t O1 = 16384;             // output_beta       (4096,4)
constexpr size_t O2 = 32768;             // alpha_softmax     (9,4096,4)
constexpr size_t O3 = 180224;            // beta_softmax      (9,4096,4)
constexpr size_t O4 = 327680;            // delta_pred_offset (9,4096,4)
constexpr size_t O5 = 475136;            // delta_pred_offset (9,4096,4)
constexpr size_t O6 = 622592;            // alpha             (9,4096,4)
constexpr size_t O7 = 770048;            // beta_out          (9,4096,4)
constexpr size_t O8 = 917504;            // cls_score         (9,4096,21)
constexpr size_t O9 = 1691648;           // alpha_softmax_cls (9,4096,1)
constexpr size_t O10 = 1728512;          // beta_softmax_cls
constexpr size_t O11 = 1765376;          // alpha_cls
constexpr size_t O12 = 1802240;          // beta_out_cls

// prep_cast block ranges
constexpr int CAST_B = 36864;            // AN*NN*DORI/8/256
constexpr int ATT_B  = 256;              // (2048/64)*(512/64)
constexpr int PQ_B   = 3200;             // NB*QCOLS*DAPP/256
constexpr int PS_B   = 72;               // AN*DORI/256
constexpr int GT_B   = 4096;             // NN*DORI/8/256
constexpr int PREP_TOTAL = CAST_B + ATT_B + PQ_B + PS_B + GT_B;   // 44488

DEVI u16 f2b(float f) {                   // f32 -> bf16 RNE (internal use only)
  unsigned u = __float_as_uint(f);
  unsigned r = (u + 0x7fffu + ((u >> 16) & 1u)) >> 16;
  return (u16)r;
}

DEVI uint4 pack8(float4 u, float4 v) {    // 8 f32 -> 8 bf16 packed
  uint4 r;
  r.x = (unsigned)f2b(u.x) | ((unsigned)f2b(u.y) << 16);
  r.y = (unsigned)f2b(u.z) | ((unsigned)f2b(u.w) << 16);
  r.z = (unsigned)f2b(v.x) | ((unsigned)f2b(v.y) << 16);
  r.w = (unsigned)f2b(v.z) | ((unsigned)f2b(v.w) << 16);
  return r;
}

DEVI void gload_lds16(const u16* g, u16* l) {   // 16B global -> LDS direct
  __builtin_amdgcn_global_load_lds(
      (const __attribute__((address_space(1))) void*)g,
      (__attribute__((address_space(3))) void*)l, 16, 0, 0);
}

// ================= prep_cast: cast | att-transpose | pack_q | pack_small | gt ======
__global__ __launch_bounds__(256) void prep_cast(const float* __restrict__ features,
                                                 const float* __restrict__ att,
                                                 const float* __restrict__ wq,
                                                 const float* __restrict__ wqc,
                                                 const float* __restrict__ wk,
                                                 const float* __restrict__ wkc,
                                                 const float* __restrict__ aw,
                                                 const float* __restrict__ bb,
                                                 const float* __restrict__ awc,
                                                 const float* __restrict__ cw,
                                                 const float* __restrict__ gt,
                                                 u16* __restrict__ featB,
                                                 u16* __restrict__ attB,
                                                 u16* __restrict__ Wq,
                                                 u16* __restrict__ Wsm) {
  __shared__ float tile[64][65];
  const int b = blockIdx.x, tid = threadIdx.x;
  if (b < CAST_B) {                                 // features f32 -> featB[0..8]
    if (!featB) return;
    long i = (long)b * 256 + tid;
    float4 v0 = ((const float4*)features)[i * 2];
    float4 v1 = ((const float4*)features)[i * 2 + 1];
    ((uint4*)featB)[i] = pack8(v0, v1);
  } else if (b < CAST_B + ATT_B) {                  // attB[c][d] = att[d][c], LDS tile
    int b2 = b - CAST_B;
    int d0 = (b2 >> 3) * 64, c0 = (b2 & 7) * 64;
#pragma unroll
    for (int r = 0; r < 16; ++r) {
      int dl = r * 4 + (tid >> 6), cl = tid & 63;
      tile[dl][cl] = att[(size_t)(d0 + dl) * DAPP + c0 + cl];
    }
    __syncthreads();
#pragma unroll
    for (int w = 0; w < 16; ++w) {
      int cl = w * 4 + (tid >> 6), dl = tid & 63;
      attB[(size_t)(c0 + cl) * DORI + d0 + dl] = f2b(tile[dl][cl]);
    }
  } else if (b < CAST_B + ATT_B + PQ_B) {           // Wq[b][160][512]
    int t = (b - CAST_B - ATT_B) * 256 + tid;
    int bq = t / (QCOLS * DAPP);
    int r = t % (QCOLS * DAPP);
    int col = r / DAPP, d = r % DAPP;
    float v;
    if (bq < 9) {
      if (col < 128) v = wq[(size_t)bq * DAPP * 128 + (size_t)d * 128 + col];
      else           v = wqc[(size_t)bq * DAPP * 32 + (size_t)d * 32 + (col - 128)];
    } else {
      if (col < 128) v = wk[(size_t)d * 128 + col];
      else           v = wkc[(size_t)d * 32 + (col - 128)];
    }
    Wq[t] = f2b(v);
  } else if (b < CAST_B + ATT_B + PQ_B + PS_B) {    // Wsmall[a][32][2048]
    int t = (b - CAST_B - ATT_B - PQ_B) * 256 + tid;
    if (t >= AN * DORI) return;
    int a = t / DORI, f = t % DORI;
    u16* Wa = Wsm + (size_t)a * 32 * DORI;
    for (int c = 0; c < 4; ++c)  Wa[c * DORI + f]       = f2b(aw[((size_t)a * DORI + f) * 4 + c]);
    for (int c = 0; c < 4; ++c)  Wa[(4 + c) * DORI + f] = f2b(bb[((size_t)a * DORI + f) * 4 + c]);
    for (int c = 0; c < 21; ++c) Wa[(8 + c) * DORI + f] = f2b(cw[((size_t)a * DORI + f) * 21 + c]);
    Wa[29 * DORI + f] = f2b(awc[(size_t)a * DORI + f]);
    Wa[30 * DORI + f] = 0;
    Wa[31 * DORI + f] = 0;
  } else {                                          // gt_features -> featB[9]
    if (!featB) return;
    long i = (long)(b - CAST_B - ATT_B - PQ_B - PS_B) * 256 + tid;
    float4 v0 = ((const float4*)gt)[i * 2];
    float4 v1 = ((const float4*)gt)[i * 2 + 1];
    ((uint4*)(featB + (size_t)AN * NN * DORI))[i] = pack8(v0, v1);
  }
}

// ================= gemm_main: off (bx<4) + smallf/cls (bx==4) in one grid ==========
// grid (5, 32, 10), 256 threads; XCD-chunked swizzle over 1600 blocks
__global__ __launch_bounds__(256) void gemm_main(const u16* __restrict__ featB,
                                                 const u16* __restrict__ attB,
                                                 const u16* __restrict__ Wsm,
                                                 u16* __restrict__ offb,
                                                 float* __restrict__ smallf,
                                                 float* __restrict__ cls_out) {
  __shared__ __align__(16) u16 As[128 * 32];
  __shared__ __align__(16) u16 Bs[128 * 32];

  int bx = blockIdx.x, by = blockIdx.y, bz = blockIdx.z;
  {                                   // nwg = 1600, cpx = 200
    int h = bx + 5 * (by + 32 * bz);
    int l = (h & 7) * 200 + (h >> 3);
    bx = l % 5; l /= 5; by = l % 32; bz = l / 32;
  }
  const int tid = threadIdx.x, lane = tid & 63, w = tid >> 6;
  const bool small = (bx == 4);
  if (small && bz == 9) return;       // no small path for gt batch
  const int tileM = by * 128;
  const u16* Ab = featB + ((size_t)bz * NN + tileM) * DORI;
  const u16* Bb = small ? (Wsm + (size_t)bz * 32 * DORI)
                        : (attB + (size_t)bx * 128 * DORI);

  f32x4 accM[4][4], accS[2][2];
#pragma unroll
  for (int i = 0; i < 4; ++i)
#pragma unroll
    for (int j = 0; j < 4; ++j) accM[i][j] = (f32x4){0.f, 0.f, 0.f, 0.f};
#pragma unroll
  for (int i = 0; i < 2; ++i)
#pragma unroll
    for (int j = 0; j < 2; ++j) accS[i][j] = (f32x4){0.f, 0.f, 0.f, 0.f};

  const int wm = w & 1, wn = w >> 1;
  const u16* ArM = As + (wm * 64 + (lane & 15)) * 32 + (lane >> 4) * 8;
  const u16* BrM = Bs + (wn * 64 + (lane & 15)) * 32 + (lane >> 4) * 8;
  const u16* ArS = As + (w * 32 + (lane & 15)) * 32 + (lane >> 4) * 8;
  const u16* BrS = Bs + ((lane & 15)) * 32 + (lane >> 4) * 8;

  for (int k0 = 0; k0 < DORI; k0 += 32) {
#pragma unroll
    for (int i = 0; i < 2; ++i) {                   // A: 512 chunks
      int c = tid + i * 256;
      gload_lds16(Ab + (size_t)(c >> 2) * DORI + k0 + (c & 3) * 8, As + c * 8);
    }
    if (small) {                                    // B: 128 chunks
      if (tid < 128)
        gload_lds16(Bb + (size_t)(tid >> 2) * DORI + k0 + (tid & 3) * 8, Bs + tid * 8);
    } else {                                        // B: 512 chunks
#pragma unroll
      for (int i = 0; i < 2; ++i) {
        int c = tid + i * 256;
        gload_lds16(Bb + (size_t)(c >> 2) * DORI + k0 + (c & 3) * 8, Bs + c * 8);
      }
    }
    __syncthreads();
    if (small) {
      s16x8 af[2], bf[2];
#pragma unroll
      for (int i = 0; i < 2; ++i) af[i] = *(const s16x8*)(ArS + i * 16 * 32);
#pragma unroll
      for (int j = 0; j < 2; ++j) bf[j] = *(const s16x8*)(BrS + j * 16 * 32);
#pragma unroll
      for (int i = 0; i < 2; ++i)
#pragma unroll
        for (int j = 0; j < 2; ++j)
          accS[i][j] = __builtin_amdgcn_mfma_f32_16x16x32_bf16(af[i], bf[j], accS[i][j], 0, 0, 0);
    } else {
      s16x8 af[4], bf[4];
#pragma unroll
      for (int i = 0; i < 4; ++i) af[i] = *(const s16x8*)(ArM + i * 16 * 32);
#pragma unroll
      for (int j = 0; j < 4; ++j) bf[j] = *(const s16x8*)(BrM + j * 16 * 32);
#pragma unroll
      for (int i = 0; i < 4; ++i)
#pragma unroll
        for (int j = 0; j < 4; ++j)
          accM[i][j] = __builtin_amdgcn_mfma_f32_16x16x32_bf16(af[i], bf[j], accM[i][j], 0, 0, 0);
    }
    __syncthreads();
  }

  if (small) {
#pragma unroll
    for (int i = 0; i < 2; ++i)
#pragma unroll
      for (int j = 0; j < 2; ++j)
#pragma unroll
        for (int q = 0; q < 4; ++q) {
          const int row = tileM + w * 32 + i * 16 + (lane >> 4) * 4 + q;
          const int col = j * 16 + (lane & 15);
          const size_t an = (size_t)bz * NN + row;
          float v = accS[i][j][q];
          smallf[an * 32 + col] = v;
          if (col >= 8 && col <= 28) cls_out[an * 21 + (col - 8)] = v;
        }
  } else {
    const int r0 = tileM + wm * 64 + (lane >> 4) * 4;
    const int c0 = bx * 128 + wn * 64 + (lane & 15);
#pragma unroll
    for (int i = 0; i < 4; ++i)
#pragma unroll
      for (int j = 0; j < 4; ++j)
#pragma unroll
        for (int q = 0; q < 4; ++q)
          offb[((size_t)bz * NN + r0 + i * 16 + q) * DAPP + c0 + j * 16] =
              f2b(fmaxf(accM[i][j][q], 0.f));
  }
}

// ================= bf16 GEMM with global_load_lds staging (key path) ===============
template<int BM, int BN, int WM, int WN, bool RELU, bool OUTBF, bool SWZ>
__global__ __launch_bounds__(WM * WN * 64)
void gemm_glds(const u16* __restrict__ A, long sA, const u16* __restrict__ B, long sB,
               void* __restrict__ Cv, long sC, int N, int K) {
  constexpr int THREADS = WM * WN * 64;
  constexpr int WTM = BM / WM, WTN = BN / WN;
  constexpr int FM = WTM / 16, FN = WTN / 16;
  constexpr int ACHN = BM * 4, BCHN = BN * 4;
  constexpr int ACH = (ACHN + THREADS - 1) / THREADS;
  constexpr int BCH = (BCHN + THREADS - 1) / THREADS;
  constexpr bool AFULL = (ACHN % THREADS) == 0, BFULL = (BCHN % THREADS) == 0;

  __shared__ __align__(16) u16 As[BM * 32];
  __shared__ __align__(16) u16 Bs[BN * 32];

  int bx = blockIdx.x, by = blockIdx.y, bz = blockIdx.z;
  if constexpr (SWZ) {
    int gx = gridDim.x, gy = gridDim.y;
    int h = bx + gx * (by + gy * bz);
    int nwg = gx * gy * (int)gridDim.z;
    int cpx = nwg >> 3;
    int l = (h & 7) * cpx + (h >> 3);
    bx = l % gx; l /= gx; by = l % gy; bz = l / gy;
  }

  const int tid = threadIdx.x, lane = tid & 63, wave = tid >> 6;
  const int wm = wave % WM, wn = wave / WM;
  const int tileN = bx * BN, tileM = by * BM;
  const u16* Ab = A + (size_t)bz * sA + (size_t)tileM * K;
  const u16* Bb = B + (size_t)bz * sB + (size_t)tileN * K;

  f32x4 acc[FM][FN];
#pragma unroll
  for (int i = 0; i < FM; ++i)
#pragma unroll
    for (int j = 0; j < FN; ++j) acc[i][j] = (f32x4){0.f, 0.f, 0.f, 0.f};

  const u16* Arow = As + (wm * WTM + (lane & 15)) * 32 + (lane >> 4) * 8;
  const u16* Brow = Bs + (wn * WTN + (lane & 15)) * 32 + (lane >> 4) * 8;

  for (int k0 = 0; k0 < K; k0 += 32) {
#pragma unroll
    for (int i = 0; i < ACH; ++i) {
      int c = tid + i * THREADS;
      if (AFULL || c < ACHN)
        gload_lds16(Ab + (size_t)(c >> 2) * K + k0 + (c & 3) * 8, As + c * 8);
    }
#pragma unroll
    for (int i = 0; i < BCH; ++i) {
      int c = tid + i * THREADS;
      if (BFULL || c < BCHN)
        gload_lds16(Bb + (size_t)(c >> 2) * K + k0 + (c & 3) * 8, Bs + c * 8);
    }
    __syncthreads();
    s16x8 af[FM], bfr[FN];
#pragma unroll
    for (int i = 0; i < FM; ++i) af[i] = *(const s16x8*)(Arow + i * 16 * 32);
#pragma unroll
    for (int j = 0; j < FN; ++j) bfr[j] = *(const s16x8*)(Brow + j * 16 * 32);
#pragma unroll
    for (int i = 0; i < FM; ++i)
#pragma unroll
      for (int j = 0; j < FN; ++j)
        acc[i][j] = __builtin_amdgcn_mfma_f32_16x16x32_bf16(af[i], bfr[j], acc[i][j], 0, 0, 0);
    __syncthreads();
  }

  const int r0 = tileM + wm * WTM + (lane >> 4) * 4;
  const int c0 = tileN + wn * WTN + (lane & 15);
#pragma unroll
  for (int i = 0; i < FM; ++i)
#pragma unroll
    for (int j = 0; j < FN; ++j)
#pragma unroll
      for (int q = 0; q < 4; ++q) {
        float v = acc[i][j][q];
        if (RELU) v = fmaxf(v, 0.f);
        size_t idx = (size_t)bz * sC + (size_t)(r0 + i * 16 + q) * N + (c0 + j * 16);
        if (OUTBF) ((u16*)Cv)[idx] = f2b(v);
        else       ((float*)Cv)[idx] = v;
      }
}

// ================= fallback gemm (A = f32, reg-staged pack) ========================
template<int BM, int BN, int WM, int WN, bool RELU, bool OUTBF>
__global__ __launch_bounds__(WM * WN * 64)
void gemm_af32(const float* __restrict__ Av, const float* __restrict__ A2v, long sA,
               const u16* __restrict__ B, long sB,
               void* __restrict__ Cv, long sC, int N, int K) {
  constexpr int THREADS = WM * WN * 64;
  constexpr int WTM = BM / WM, WTN = BN / WN;
  constexpr int FM = WTM / 16, FN = WTN / 16;
  constexpr int ACH = (BM * 4) / THREADS;
  constexpr int BCHN = BN * 4;
  constexpr int BCH = (BCHN + THREADS - 1) / THREADS;
  constexpr bool BFULL = (BCHN % THREADS) == 0;

  __shared__ __align__(16) u16 As[BM * 32];
  __shared__ __align__(16) u16 Bs[BN * 32];

  const int tid = threadIdx.x, lane = tid & 63, wave = tid >> 6;
  const int wm = wave % WM, wn = wave / WM;
  const int tileN = blockIdx.x * BN, tileM = blockIdx.y * BM;
  const int batch = blockIdx.z;
  const float* base = (batch < 9) ? (Av + (size_t)batch * sA) : A2v;
  const float* Ab32 = base + (size_t)tileM * K;
  const u16* Bb = B + (size_t)batch * sB + (size_t)tileN * K;

  f32x4 acc[FM][FN];
#pragma unroll
  for (int i = 0; i < FM; ++i)
#pragma unroll
    for (int j = 0; j < FN; ++j) acc[i][j] = (f32x4){0.f, 0.f, 0.f, 0.f};

  uint4 ra[ACH], rb[BCH];
  auto load_t = [&](int k0) {
#pragma unroll
    for (int i = 0; i < ACH; ++i) {
      int c = tid + i * THREADS;
      const float* s = Ab32 + (size_t)(c >> 2) * K + k0 + (c & 3) * 8;
      ra[i] = pack8(*(const float4*)s, *(const float4*)(s + 4));
    }
#pragma unroll
    for (int i = 0; i < BCH; ++i) {
      int c = tid + i * THREADS;
      if (BFULL || c < BCHN)
        rb[i] = *(const uint4*)(Bb + (size_t)(c >> 2) * K + k0 + (c & 3) * 8);
    }
  };

  load_t(0);
  const u16* Arow = As + (wm * WTM + (lane & 15)) * 32 + (lane >> 4) * 8;
  const u16* Brow = Bs + (wn * WTN + (lane & 15)) * 32 + (lane >> 4) * 8;

  for (int k0 = 0; k0 < K; k0 += 32) {
    __syncthreads();
#pragma unroll
    for (int i = 0; i < ACH; ++i)
      *(uint4*)(As + (size_t)(tid + i * THREADS) * 8) = ra[i];
#pragma unroll
    for (int i = 0; i < BCH; ++i) {
      int c = tid + i * THREADS;
      if (BFULL || c < BCHN) *(uint4*)(Bs + (size_t)c * 8) = rb[i];
    }
    __syncthreads();
    if (k0 + 32 < K) load_t(k0 + 32);
    s16x8 af[FM], bfr[FN];
#pragma unroll
    for (int i = 0; i < FM; ++i) af[i] = *(const s16x8*)(Arow + i * 16 * 32);
#pragma unroll
    for (int j = 0; j < FN; ++j) bfr[j] = *(const s16x8*)(Brow + j * 16 * 32);
#pragma unroll
    for (int i = 0; i < FM; ++i)
#pragma unroll
      for (int j = 0; j < FN; ++j)
        acc[i][j] = __builtin_amdgcn_mfma_f32_16x16x32_bf16(af[i], bfr[j], acc[i][j], 0, 0, 0);
  }

  const int r0 = tileM + wm * WTM + (lane >> 4) * 4;
  const int c0 = tileN + wn * WTN + (lane & 15);
#pragma unroll
  for (int i = 0; i < FM; ++i)
#pragma unroll
    for (int j = 0; j < FN; ++j)
#pragma unroll
      for (int q = 0; q < 4; ++q) {
        float v = acc[i][j][q];
        if (RELU) v = fmaxf(v, 0.f);
        size_t idx = (size_t)batch * sC + (size_t)(r0 + i * 16 + q) * N + (c0 + j * 16);
        if (OUTBF) ((u16*)Cv)[idx] = f2b(v);
        else       ((float*)Cv)[idx] = v;
      }
}

// ================= cls copy (fallback path only) ===================================
__global__ __launch_bounds__(256) void cls_copy(const float* __restrict__ smallf,
                                                float* __restrict__ o) {
  int i = blockIdx.x * blockDim.x + threadIdx.x;
  if (i >= AN * NN * NCLS) return;
  int an = i / NCLS, c = i % NCLS;
  o[i] = smallf[(size_t)an * 32 + 8 + c];
}

// ================= fused q-projection + beta epilogue ==============================
__global__ __launch_bounds__(256) void gemm2qb(const u16* __restrict__ offb,
                                               const u16* __restrict__ Wq,
                                               const float* __restrict__ keyf,
                                               const float* __restrict__ ious,
                                               float* __restrict__ betaf,
                                               float* __restrict__ betac) {
  constexpr int BM = 128, BN = 160;
  __shared__ __align__(16) u16 As[BM * 32];
  __shared__ __align__(16) u16 Bs[BN * 32];
  const int tid = threadIdx.x, lane = tid & 63, wave = tid >> 6;  // 4 waves on M
  const int tileM = blockIdx.x * BM;
  const int a = blockIdx.y;
  const u16* Ab = offb + ((size_t)a * NN + tileM) * DAPP;
  const u16* Bb = Wq + (size_t)a * QCOLS * DAPP;

  f32x4 acc[2][10];
#pragma unroll
  for (int i = 0; i < 2; ++i)
#pragma unroll
    for (int j = 0; j < 10; ++j) acc[i][j] = (f32x4){0.f, 0.f, 0.f, 0.f};

  const u16* Arow = As + (wave * 32 + (lane & 15)) * 32 + (lane >> 4) * 8;
  const u16* Brow = Bs + (lane & 15) * 32 + (lane >> 4) * 8;

  for (int k0 = 0; k0 < DAPP; k0 += 32) {
#pragma unroll
    for (int i = 0; i < 2; ++i) {          // ACHN = 512
      int c = tid + i * 256;
      gload_lds16(Ab + (size_t)(c >> 2) * DAPP + k0 + (c & 3) * 8, As + c * 8);
    }
#pragma unroll
    for (int i = 0; i < 3; ++i) {          // BCHN = 640
      int c = tid + i * 256;
      if (c < 640)
        gload_lds16(Bb + (size_t)(c >> 2) * DAPP + k0 + (c & 3) * 8, Bs + c * 8);
    }
    __syncthreads();
    s16x8 af[2], bfr[10];
#pragma unroll
    for (int i = 0; i < 2; ++i) af[i] = *(const s16x8*)(Arow + i * 16 * 32);
#pragma unroll
    for (int j = 0; j < 10; ++j) bfr[j] = *(const s16x8*)(Brow + j * 16 * 32);
#pragma unroll
    for (int i = 0; i < 2; ++i)
#pragma unroll
      for (int j = 0; j < 10; ++j)
        acc[i][j] = __builtin_amdgcn_mfma_f32_16x16x32_bf16(af[i], bfr[j], acc[i][j], 0, 0, 0);
    __syncthreads();
  }

  const float scale = 0.17677669529663687f;  // 1/sqrt(32)
  const int cg = lane & 15;
#pragma unroll
  for (int i = 0; i < 2; ++i)
#pragma unroll
    for (int q = 0; q < 4; ++q) {
      const int row = tileM + wave * 32 + i * 16 + (lane >> 4) * 4 + q;
      const float* kr = keyf + (size_t)row * QCOLS;
      float m = 0.f;
#pragma unroll
      for (int j = 0; j < 8; ++j) m += acc[i][j][q] * kr[cg + j * 16];
      float cl = acc[i][8][q] * kr[128 + cg] + acc[i][9][q] * kr[144 + cg];
      m += __shfl_xor(m, 4); m += __shfl_xor(m, 8);
      cl += __shfl_xor(cl, 1); cl += __shfl_xor(cl, 2);
      cl += __shfl_xor(cl, 4); cl += __shfl_xor(cl, 8);
      const float iou = ious[(size_t)a * NN + row];
      if (cg < 4)  betaf[((size_t)a * NN + row) * 4 + (lane & 3)] = m * scale - iou;
      if (cg == 0) betac[(size_t)a * NN + row] = cl * scale - iou;
    }
}

// ================= softmaxes + outputs, thread per (n,c) ===========================
__global__ __launch_bounds__(256) void finalize(const float* __restrict__ smallf,
                                                const float* __restrict__ beta_ws,
                                                const float* __restrict__ betac_ws,
                                                const float* __restrict__ delta_rois,
                                                float* __restrict__ out) {
  int t = blockIdx.x * 256 + threadIdx.x;      // grid = NN*4/256 = 64
  if (t >= NN * 4) return;
  const int n = t >> 2, c = t & 3;

  {
    float al[9], be[9], dp[9];
    float mA = -1e30f, mB = -1e30f;
    for (int a = 0; a < 9; ++a) {
      size_t an = (size_t)a * NN + n;
      al[a] = smallf[an * 32 + c];
      float off_ = smallf[an * 32 + 4 + c];
      dp[a] = delta_rois[an * 5 + 1 + c] + off_;
      be[a] = beta_ws[an * 4 + c];
      mA = fmaxf(mA, al[a]); mB = fmaxf(mB, be[a]);
    }
    float eA[9], eB[9], sA = 0.f, sB = 0.f;
    for (int a = 0; a < 9; ++a) {
      eA[a] = expf(al[a] - mA); sA += eA[a];
      eB[a] = expf(be[a] - mB); sB += eB[a];
    }
    float rA = 1.f / sA, rB = 1.f / sB;
    float ov = 0.f, obv = 0.f;
    for (int a = 0; a < 9; ++a) {
      size_t an = (size_t)a * NN + n;
      float as_ = eA[a] * rA, bs_ = eB[a] * rB;
      out[O2 + an * 4 + c] = as_;
      out[O3 + an * 4 + c] = bs_;
      out[O4 + an * 4 + c] = dp[a];
      out[O5 + an * 4 + c] = dp[a];
      out[O6 + an * 4 + c] = al[a];
      out[O7 + an * 4 + c] = be[a];
      ov += dp[a] * as_; obv += dp[a] * bs_;
    }
    out[O0 + (size_t)n * 4 + c] = ov;
    out[O1 + (size_t)n * 4 + c] = obv;
  }

  if (c == 0) {
    float ac[9], bc[9];
    float mA = -1e30f, mB = -1e30f;
    for (int a = 0; a < 9; ++a) {
      size_t an = (size_t)a * NN + n;
      ac[a] = smallf[an * 32 + 29];
      bc[a] = betac_ws[an];
      mA = fmaxf(mA, ac[a]); mB = fmaxf(mB, bc[a]);
    }
    float eA[9], eB[9], sA = 0.f, sB = 0.f;
    for (int a = 0; a < 9; ++a) {
      eA[a] = expf(ac[a] - mA); sA += eA[a];
      eB[a] = expf(bc[a] - mB); sB += eB[a];
    }
    float rA = 1.f / sA, rB = 1.f / sB;
    for (int a = 0; a < 9; ++a) {
      size_t an = (size_t)a * NN + n;
      out[O9 + an]  = eA[a] * rA;
      out[O10 + an] = eB[a] * rB;
      out[O11 + an] = ac[a];
      out[O12 + an] = bc[a];
    }
  }
}

extern "C" void kernel_launch(void* const* d_in, const int* in_sizes, int n_in,
                              void* d_out, int out_size, void* d_ws, size_t ws_size,
                              hipStream_t stream) {
  const float* delta_rois = (const float*)d_in[1];
  const float* features   = (const float*)d_in[2];
  const float* gt_features= (const float*)d_in[3];
  const float* ious       = (const float*)d_in[4];
  const float* att        = (const float*)d_in[5];
  const float* w_k        = (const float*)d_in[6];
  const float* w_q        = (const float*)d_in[7];
  const float* alpha_w    = (const float*)d_in[8];
  const float* bbox       = (const float*)d_in[9];
  const float* w_k_cls    = (const float*)d_in[10];
  const float* w_q_cls    = (const float*)d_in[11];
  const float* alpha_w_cls= (const float*)d_in[12];
  const float* cls_w      = (const float*)d_in[13];
  float* out = (float*)d_out;

  char* ws = (char*)d_ws;
  u16* attB    = (u16*)ws;   ws += (size_t)DAPP * DORI * 2;       // 2.1 MB
  u16* Wq      = (u16*)ws;   ws += (size_t)NB * QCOLS * DAPP * 2; // 1.6 MB
  u16* Wsmall  = (u16*)ws;   ws += (size_t)AN * 32 * DORI * 2;    // 1.2 MB
  u16* offb    = (u16*)ws;   ws += (size_t)NB * NN * DAPP * 2;    // 42 MB (batch9 = gt_off)
  float* smallf= (float*)ws; ws += (size_t)AN * NN * 32 * 4;      // 4.7 MB
  float* keyf  = (float*)ws; ws += (size_t)NN * QCOLS * 4;        // 2.6 MB
  float* betaf = (float*)ws; ws += (size_t)AN * NN * 4 * 4;       // 2.4 MB
  float* betac = (float*)ws; ws += (size_t)AN * NN * 4;           // 0.15 MB
  size_t base_bytes = (size_t)(ws - (char*)d_ws);
  size_t featB_bytes = (size_t)NB * NN * DORI * 2;                // 168 MB
  bool big = ws_size >= base_bytes + featB_bytes;
  u16* featB = big ? (u16*)ws : nullptr;

  // 1. fused prep + full-feature cast (one launch)
  prep_cast<<<PREP_TOTAL, 256, 0, stream>>>(features, att, w_q, w_q_cls, w_k, w_k_cls,
                                            alpha_w, bbox, alpha_w_cls, cls_w,
                                            gt_features, featB, attB, Wq, Wsmall);

  if (big) {
    // 2. off + smallf + cls in one grid (5,32,10), XCD swizzle
    dim3 gm(5, 32, NB);
    gemm_main<<<gm, 256, 0, stream>>>(featB, attB, Wsmall, offb, smallf, out + O8);
  } else {
    dim3 g1(DAPP / 128, NN / 128, NB);
    gemm_af32<128, 128, 2, 2, true, true><<<g1, 256, 0, stream>>>(
        features, gt_features, (long)NN * DORI, attB, 0, offb, (long)NN * DAPP, DAPP, DORI);
    dim3 gsm(1, NN / 128, AN);
    gemm_af32<128, 32, 4, 1, false, false><<<gsm, 256, 0, stream>>>(
        features, nullptr, (long)NN * DORI, Wsmall, (long)32 * DORI,
        smallf, (long)NN * 32, 32, DORI);
    cls_copy<<<(AN * NN * NCLS + 255) / 256, 256, 0, stream>>>(smallf, out + O8);
  }

  // 3. key = gt_off @ Wq[9]^T (batch 9) -> keyf f32
  dim3 gk(QCOLS / 32, NN / 128, 1);
  gemm_glds<128, 32, 4, 1, false, false, false><<<gk, 256, 0, stream>>>(
      offb + (size_t)9 * NN * DAPP, 0, Wq + (size_t)9 * QCOLS * DAPP, 0,
      keyf, 0, QCOLS, DAPP);

  // 4. fused q-projection + beta (batches 0-8)
  dim3 g2(NN / 128, AN, 1);
  gemm2qb<<<g2, 256, 0, stream>>>(offb, Wq, keyf, ious, betaf, betac);

  // 5. softmaxes + outputs
  finalize<<<NN * 4 / 256, 256, 0, stream>>>(smallf, betaf, betac, delta_rois, out);
}